// Round 3
// baseline (591.193 us; speedup 1.0000x reference)
//
#include <hip/hip_runtime.h>
#include <hip/hip_bf16.h>
#include <stdint.h>

#define CDIM 192
#define KDIM 960
#define HW   65536
#define WI   256

// ---- workspace layouts ----
// 2-plane (legacy): XT 2*65536*192*2
#define OFF_W2    50331648u
#define OFF_BIAS2 50700288u
#define OFF_FLAG2 50701056u
#define NEED2     50701120u
// 4-plane (preferred): XT 4*65536*192*2
#define OFF_W4    100663296u
#define OFF_BIAS4 101031936u
#define OFF_FLAG4 101032704u
#define NEED4     101032768u

typedef __attribute__((ext_vector_type(8))) short short8;
typedef __attribute__((ext_vector_type(4))) float floatx4;

__device__ __forceinline__ uint16_t f2b(float v) {
    __hip_bfloat16 h = __float2bfloat16(v);
    return *reinterpret_cast<uint16_t*>(&h);
}

// ---------------- dtype detector: bf16-packed vs fp32, via low-halfword exponent stats ----------
__global__ __launch_bounds__(256) void detect_kernel(const uint32_t* __restrict__ xw,
                                                     int* __restrict__ flag) {
    __shared__ int cnt;
    if (threadIdx.x == 0) cnt = 0;
    __syncthreads();
    int local = 0;
    #pragma unroll
    for (int i = 0; i < 4; ++i) {
        int s = threadIdx.x * 4 + i;                   // 0..1023
        uint32_t d = xw[(size_t)s * 24571];            // max dword 25,136,133 < 25,165,824
        uint32_t e = (d >> 7) & 0xFF;                  // bf16 exponent field of LOW halfword
        if (e >= 110 && e <= 130) ++local;             // plausible for N(0,1) bf16
    }
    atomicAdd(&cnt, local);
    __syncthreads();
    if (threadIdx.x == 0) *flag = (cnt >= 512) ? 1 : 0;   // 1 = bf16 buffers, 0 = fp32 buffers
}

// ---------------- prep: canonicalize W -> bf16, bias -> f32 (so GEMM is dtype-free) ------------
__global__ __launch_bounds__(256) void prep_kernel(const void* __restrict__ Wsrc,
                                                   const void* __restrict__ bsrc,
                                                   __hip_bfloat16* __restrict__ Wb,
                                                   float* __restrict__ bfp,
                                                   const int* __restrict__ flag) {
    const int f = *flag;
    if (blockIdx.x < 720) {
        int i = blockIdx.x * 256 + threadIdx.x;        // < 184320
        float v = f ? __bfloat162float(((const __hip_bfloat16*)Wsrc)[i])
                    : ((const float*)Wsrc)[i];
        Wb[i] = __float2bfloat16(v);
    } else if (threadIdx.x < CDIM) {
        int j = threadIdx.x;
        bfp[j] = f ? __bfloat162float(((const __hip_bfloat16*)bsrc)[j])
                   : ((const float*)bsrc)[j];
    }
}

// ---------------- transpose x[b][c][hw] -> XT[bb][pix][c] bf16 --------------------------------
__global__ __launch_bounds__(256) void transpose_kernel(const void* __restrict__ xsrc,
                                                        __hip_bfloat16* __restrict__ xt,
                                                        const int* __restrict__ flag,
                                                        int base_b) {
    __shared__ uint16_t lds16[CDIM * 64];   // 24576 B
    const int bid = blockIdx.x;
    const int tid = threadIdx.x;
    const int bb = bid >> 10;               // plane within XT (grid = nplanes*1024)
    const int b  = base_b + bb;
    const int p0 = (bid & 1023) << 6;
    const int f = *flag;
    if (f) {
        const uint4* xg = (const uint4*)xsrc;
        #pragma unroll
        for (int t = 0; t < 6; ++t) {
            int idx = tid + t * 256;
            int c = idx >> 3, j = idx & 7;
            size_t off = ((size_t)(b * CDIM + c) * HW + p0 + j * 8) >> 3;
            uint4 v = xg[off];
            int col = (j ^ ((c >> 3) & 7)) << 3;
            *(uint4*)&lds16[c * 64 + col] = v;
        }
    } else {
        const float4* xg = (const float4*)xsrc;
        #pragma unroll
        for (int t = 0; t < 6; ++t) {
            int idx = tid + t * 256;
            int c = idx >> 3, j = idx & 7;
            size_t off4 = ((size_t)(b * CDIM + c) * HW + p0 + j * 8) >> 2;
            float4 v0 = xg[off4], v1 = xg[off4 + 1];
            uint32_t w0 = f2b(v0.x) | ((uint32_t)f2b(v0.y) << 16);
            uint32_t w1 = f2b(v0.z) | ((uint32_t)f2b(v0.w) << 16);
            uint32_t w2 = f2b(v1.x) | ((uint32_t)f2b(v1.y) << 16);
            uint32_t w3 = f2b(v1.z) | ((uint32_t)f2b(v1.w) << 16);
            int col = (j ^ ((c >> 3) & 7)) << 3;
            *(uint4*)&lds16[c * 64 + col] = make_uint4(w0, w1, w2, w3);
        }
    }
    __syncthreads();
    uint4* dst = (uint4*)xt + (size_t)(bb * HW + p0) * 24;   // 24 uint4 per XT row (384 B)
    #pragma unroll
    for (int t = 0; t < 6; ++t) {
        int m = tid + t * 256;              // linear uint4 index in the 24 KB tile
        int px = m / 24, c8 = m % 24;
        int colbase = (((px >> 3) ^ (c8 & 7)) << 3) | (px & 7);
        uint32_t d[4];
        #pragma unroll
        for (int wd = 0; wd < 4; ++wd) {
            uint32_t lo = lds16[(c8 * 8 + 2 * wd) * 64 + colbase];
            uint32_t hi = lds16[(c8 * 8 + 2 * wd + 1) * 64 + colbase];
            d[wd] = lo | (hi << 16);
        }
        dst[m] = make_uint4(d[0], d[1], d[2], d[3]);
    }
}

// ---------------- MFMA GEMM  Out[o][p] = sum_s sum_c W[o][s*192+c] * XT[p+dp(s)][c] ------------
__device__ __forceinline__ void gload16(const void* g, void* l) {
    __builtin_amdgcn_global_load_lds(
        (const __attribute__((address_space(1))) uint32_t*)g,
        (__attribute__((address_space(3))) uint32_t*)l, 16, 0, 0);
}

// Depth-2 software pipeline (full 30-step unroll, all indices static):
//   B (XT) loads: issued at step k for consumption at k+2 -> 3 register sets rotating k%3.
//   W gload_lds : issued at step k for consumption at k+1 -> 2 LDS buffers (W is L2-resident).
// Per step k: barrier1 | gload W[k+1] | SB | load B[k+2] | SB | vmcnt(11) | barrier2 | compute.
// vmcnt bookkeeping (in-order retire): outstanding at wait = B[k](4),W[k](3),B[k+1](4),
// W[k+1](3),B[k+2](4) = 18 -> vmcnt(11) retires exactly {B[k], W[k]}.  k=28 -> 7, k=29 -> 0.
// The SB between W-gloads and B-loads keeps W[k+1] OLDER than B[k+2] so the counts stay exact.
__global__ __launch_bounds__(256, 2) void gemm_kernel(const __hip_bfloat16* __restrict__ xt,
                                                      const __hip_bfloat16* __restrict__ Wm,
                                                      const float* __restrict__ biasf,
                                                      void* __restrict__ outv,
                                                      const int* __restrict__ flag,
                                                      int base_b) {
    __shared__ char ldsW[2 * 12288];
    const int f = *flag;
    const int tid  = threadIdx.x;
    const int lane = tid & 63, wave = tid >> 6;
    const int quad = lane >> 4, l15 = lane & 15;

    // XCD-aware bijective swizzle (nwg % 8 == 0 for both 1024 and 2048 grids)
    const int nwg  = (int)gridDim.x;
    const int bid0 = (int)blockIdx.x;
    const int wg   = (bid0 & 7) * (nwg >> 3) + (bid0 >> 3);

    const int bb = wg >> 9;
    const int b  = base_b + bb;
    const int r  = wg & 511;
    const int h  = r >> 1;
    const int w0 = (r & 1) << 7;
    const int p0 = h * WI + w0;
    const int obase = (wave >> 1) * 96;
    const int nbase = (wave & 1) * 64;

    const char* gw[3];
    int ldsoff[3];
    #pragma unroll
    for (int t = 0; t < 3; ++t) {
        int chunk = tid + t * 256;
        int kq = chunk / 192, o = chunk % 192;
        gw[t] = (const char*)Wm + ((size_t)o * KDIM + kq * 8) * 2;
        ldsoff[t] = chunk * 16;
    }
    int aoff[6];
    #pragma unroll
    for (int mt = 0; mt < 6; ++mt) {
        int o = obase + mt * 16 + l15;
        aoff[mt] = (quad * 192 + o) * 16;
    }
    const char* xb = (const char*)(xt + (size_t)bb * HW * CDIM);
    int prow[4]; bool w255[4], wzero[4];
    #pragma unroll
    for (int nt = 0; nt < 4; ++nt) {
        int pl = nbase + nt * 16 + l15;
        prow[nt]  = p0 + pl;
        w255[nt]  = ((w0 + pl) == 255);
        wzero[nt] = ((w0 + pl) == 0);
    }

    floatx4 acc[6][4];
    #pragma unroll
    for (int mt = 0; mt < 6; ++mt)
        #pragma unroll
        for (int nt = 0; nt < 4; ++nt)
            acc[mt][nt] = (floatx4){0.f, 0.f, 0.f, 0.f};

    short8 bfr[3][4];
    bool   kil[3][4];

    // prologue: drain, then W[0] gloads (oldest), then B[0], B[1] (s=0 -> no edges)
    asm volatile("s_waitcnt vmcnt(0) lgkmcnt(0)" ::: "memory");
    __builtin_amdgcn_sched_barrier(0);
    #pragma unroll
    for (int t = 0; t < 3; ++t) gload16(gw[t], ldsW + ldsoff[t]);
    __builtin_amdgcn_sched_barrier(0);      // keep W[0] older than B[0]/B[1]
    #pragma unroll
    for (int q = 0; q < 2; ++q)
        #pragma unroll
        for (int nt = 0; nt < 4; ++nt) {
            kil[q][nt] = false;
            bfr[q][nt] = *(const short8*)(xb + ((size_t)prow[nt] * CDIM + q * 32 + quad * 8) * 2);
        }
    __builtin_amdgcn_sched_barrier(0);

    #pragma unroll
    for (int k = 0; k < 30; ++k) {
        const int cur = (k & 1) * 12288;
        __builtin_amdgcn_s_barrier();               // barrier1: all prev-step LDS reads done
        __builtin_amdgcn_sched_barrier(0);
        if (k < 29) {
            const int nxt = 12288 - cur;
            #pragma unroll
            for (int t = 0; t < 3; ++t)
                gload16(gw[t] + (size_t)(k + 1) * 64, ldsW + nxt + ldsoff[t]);
        }
        __builtin_amdgcn_sched_barrier(0);          // W[k+1] stays older than B[k+2]
        if (k + 2 < 30) {
            const int k2 = k + 2;
            const int s2 = k2 / 6, j62 = k2 % 6;    // compile-time after unroll
            const int dp  = (s2 == 1) ? 1 : (s2 == 2) ? -1 : (s2 == 3) ? WI : (s2 == 4) ? -WI : 0;
            const bool skip = (s2 == 3 && h == 255) || (s2 == 4 && h == 0);
            const int dpe = skip ? 0 : dp;
            const int slot = k2 % 3;
            #pragma unroll
            for (int nt = 0; nt < 4; ++nt) {
                const bool edge = (s2 == 1 && w255[nt]) || (s2 == 2 && wzero[nt]);
                kil[slot][nt] = (edge || skip);
                const int rowi = edge ? prow[nt] : (prow[nt] + dpe);
                bfr[slot][nt] = *(const short8*)(xb +
                    ((size_t)rowi * CDIM + j62 * 32 + quad * 8) * 2);
            }
        }
        __builtin_amdgcn_sched_barrier(0);
        if (k < 28)       asm volatile("s_waitcnt vmcnt(11)" ::: "memory");
        else if (k == 28) asm volatile("s_waitcnt vmcnt(7)" ::: "memory");
        else              asm volatile("s_waitcnt vmcnt(0)" ::: "memory");
        __builtin_amdgcn_sched_barrier(0);
        __builtin_amdgcn_s_barrier();               // barrier2: W[k] visible to all waves
        __builtin_amdgcn_sched_barrier(0);

        short8 af[6];
        #pragma unroll
        for (int mt = 0; mt < 6; ++mt)
            af[mt] = *(const short8*)(ldsW + cur + aoff[mt]);
        const int cs = k % 3;
        short8 bf[4];
        #pragma unroll
        for (int nt = 0; nt < 4; ++nt)
            bf[nt] = kil[cs][nt] ? (short8){0, 0, 0, 0, 0, 0, 0, 0} : bfr[cs][nt];

        __builtin_amdgcn_s_setprio(1);
        #pragma unroll
        for (int mt = 0; mt < 6; ++mt)
            #pragma unroll
            for (int nt = 0; nt < 4; ++nt)
                acc[mt][nt] = __builtin_amdgcn_mfma_f32_16x16x32_bf16(
                    af[mt], bf[nt], acc[mt][nt], 0, 0, 0);
        __builtin_amdgcn_s_setprio(0);
    }

    // epilogue: + bias; D layout: row(o) = quad*4+reg, col(px) = lane&15
    #pragma unroll
    for (int mt = 0; mt < 6; ++mt) {
        int o0 = obase + mt * 16 + quad * 4;
        float bv[4];
        #pragma unroll
        for (int rr = 0; rr < 4; ++rr) bv[rr] = biasf[o0 + rr];
        #pragma unroll
        for (int nt = 0; nt < 4; ++nt) {
            int px = nbase + nt * 16 + l15;
            size_t base = ((size_t)(b * CDIM + o0) * HW) + p0 + px;
            if (f) {
                __hip_bfloat16* out = (__hip_bfloat16*)outv;
                #pragma unroll
                for (int rr = 0; rr < 4; ++rr)
                    out[base + (size_t)rr * HW] = __float2bfloat16(acc[mt][nt][rr] + bv[rr]);
            } else {
                float* out = (float*)outv;
                #pragma unroll
                for (int rr = 0; rr < 4; ++rr)
                    out[base + (size_t)rr * HW] = acc[mt][nt][rr] + bv[rr];
            }
        }
    }
}

// ---------------- fallback: naive direct conv, dtype-aware, no big workspace -------------------
__global__ __launch_bounds__(256) void fallback_kernel(const void* __restrict__ xv,
                                                       const void* __restrict__ Wv,
                                                       const void* __restrict__ bv,
                                                       void* __restrict__ outv,
                                                       const int* __restrict__ flag) {
    __shared__ float Wl[KDIM];
    const int f = *flag;
    const int tid = threadIdx.x;
    const int bid = blockIdx.x;
    const int h = bid & 255;
    const int bo = bid >> 8;
    const int o = bo % CDIM;
    const int b = bo / CDIM;
    if (f) {
        const __hip_bfloat16* W16 = (const __hip_bfloat16*)Wv;
        for (int i = tid; i < KDIM; i += 256) Wl[i] = __bfloat162float(W16[(size_t)o * KDIM + i]);
    } else {
        const float* W32 = (const float*)Wv;
        for (int i = tid; i < KDIM; i += 256) Wl[i] = W32[(size_t)o * KDIM + i];
    }
    __syncthreads();
    const size_t pb = (size_t)b * CDIM * HW + (size_t)h * WI + tid;
    float acc = f ? __bfloat162float(((const __hip_bfloat16*)bv)[o]) : ((const float*)bv)[o];
    if (f) {
        const __hip_bfloat16* x = (const __hip_bfloat16*)xv;
        for (int c = 0; c < CDIM; ++c) {
            const __hip_bfloat16* xp = x + pb + (size_t)c * HW;
            float ctr = __bfloat162float(xp[0]);
            float rgt = (tid < 255) ? __bfloat162float(xp[1])   : 0.f;
            float lft = (tid > 0)   ? __bfloat162float(xp[-1])  : 0.f;
            float dwn = (h < 255)   ? __bfloat162float(xp[WI])  : 0.f;
            float up  = (h > 0)     ? __bfloat162float(xp[-WI]) : 0.f;
            acc += ctr * Wl[c] + rgt * Wl[192 + c] + lft * Wl[384 + c]
                 + dwn * Wl[576 + c] + up * Wl[768 + c];
        }
    } else {
        const float* x = (const float*)xv;
        for (int c = 0; c < CDIM; ++c) {
            const float* xp = x + pb + (size_t)c * HW;
            float ctr = xp[0];
            float rgt = (tid < 255) ? xp[1]   : 0.f;
            float lft = (tid > 0)   ? xp[-1]  : 0.f;
            float dwn = (h < 255)   ? xp[WI]  : 0.f;
            float up  = (h > 0)     ? xp[-WI] : 0.f;
            acc += ctr * Wl[c] + rgt * Wl[192 + c] + lft * Wl[384 + c]
                 + dwn * Wl[576 + c] + up * Wl[768 + c];
        }
    }
    size_t oidx = (size_t)bo * HW + (size_t)h * WI + tid;
    if (f) ((__hip_bfloat16*)outv)[oidx] = __float2bfloat16(acc);
    else   ((float*)outv)[oidx] = acc;
}

extern "C" void kernel_launch(void* const* d_in, const int* in_sizes, int n_in,
                              void* d_out, int out_size, void* d_ws, size_t ws_size,
                              hipStream_t stream) {
    const uint32_t* xw = (const uint32_t*)d_in[0];
    char* ws = (char*)d_ws;

    if (ws_size >= NEED4) {
        // single pass over all 4 batches
        int* flag = (int*)(ws + OFF_FLAG4);
        __hip_bfloat16* xt = (__hip_bfloat16*)ws;
        __hip_bfloat16* Wb = (__hip_bfloat16*)(ws + OFF_W4);
        float* bfp = (float*)(ws + OFF_BIAS4);
        detect_kernel<<<1, 256, 0, stream>>>(xw, flag);
        prep_kernel<<<721, 256, 0, stream>>>(d_in[1], d_in[2], Wb, bfp, flag);
        transpose_kernel<<<4096, 256, 0, stream>>>(d_in[0], xt, flag, 0);
        gemm_kernel<<<2048, 256, 0, stream>>>(xt, Wb, bfp, d_out, flag, 0);
    } else if (ws_size >= NEED2) {
        // legacy 2-round layout, same improved kernels
        int* flag = (int*)(ws + OFF_FLAG2);
        __hip_bfloat16* xt = (__hip_bfloat16*)ws;
        __hip_bfloat16* Wb = (__hip_bfloat16*)(ws + OFF_W2);
        float* bfp = (float*)(ws + OFF_BIAS2);
        detect_kernel<<<1, 256, 0, stream>>>(xw, flag);
        prep_kernel<<<721, 256, 0, stream>>>(d_in[1], d_in[2], Wb, bfp, flag);
        for (int rnd = 0; rnd < 2; ++rnd) {
            transpose_kernel<<<2048, 256, 0, stream>>>(d_in[0], xt, flag, 2 * rnd);
            gemm_kernel<<<1024, 256, 0, stream>>>(xt, Wb, bfp, d_out, flag, 2 * rnd);
        }
    } else {
        int* flag = (int*)ws;
        detect_kernel<<<1, 256, 0, stream>>>(xw, flag);
        fallback_kernel<<<4 * CDIM * 256, 256, 0, stream>>>(d_in[0], d_in[1], d_in[2],
                                                            d_out, flag);
    }
}

// Round 4
// 464.000 us; speedup vs baseline: 1.2741x; 1.2741x over previous
//
#include <hip/hip_runtime.h>
#include <hip/hip_bf16.h>
#include <stdint.h>

#define CDIM 192
#define KDIM 960
#define HW   65536
#define WI   256

// workspace: Wb bf16 (368640 B) + bias f32 (768 B) + flag
#define OFF_BIAS 368640u
#define OFF_FLAG 369408u
#define NEED_WS  369472u

// fused-kernel LDS geometry: x slices stored TRANSPOSED [px_local:132][c:32] bf16,
// row stride 80 B (64 B data + 16 B pad -> 8-bank spread for px-consecutive lanes)
#define ROW_B    80
#define SLICE_B  10560   // 132 * 80
#define WOFF     31680   // 3 * SLICE_B
#define WBUF     12288

typedef __attribute__((ext_vector_type(8))) short short8;
typedef __attribute__((ext_vector_type(4))) float floatx4;

__device__ __forceinline__ uint16_t f2b(float v) {
    __hip_bfloat16 h = __float2bfloat16(v);
    return *reinterpret_cast<uint16_t*>(&h);
}

// ---------------- dtype detector: bf16-packed vs fp32, via low-halfword exponent stats ----------
__global__ __launch_bounds__(256) void detect_kernel(const uint32_t* __restrict__ xw,
                                                     int* __restrict__ flag) {
    __shared__ int cnt;
    if (threadIdx.x == 0) cnt = 0;
    __syncthreads();
    int local = 0;
    #pragma unroll
    for (int i = 0; i < 4; ++i) {
        int s = threadIdx.x * 4 + i;                   // 0..1023
        uint32_t d = xw[(size_t)s * 24571];            // max dword 25,136,133 < 25,165,824
        uint32_t e = (d >> 7) & 0xFF;                  // bf16 exponent field of LOW halfword
        if (e >= 110 && e <= 130) ++local;             // plausible for N(0,1) bf16
    }
    atomicAdd(&cnt, local);
    __syncthreads();
    if (threadIdx.x == 0) *flag = (cnt >= 512) ? 1 : 0;   // 1 = bf16 buffers, 0 = fp32 buffers
}

// ---------------- prep: canonicalize W -> bf16, bias -> f32 (so GEMM is dtype-free) ------------
__global__ __launch_bounds__(256) void prep_kernel(const void* __restrict__ Wsrc,
                                                   const void* __restrict__ bsrc,
                                                   __hip_bfloat16* __restrict__ Wb,
                                                   float* __restrict__ bfp,
                                                   const int* __restrict__ flag) {
    const int f = *flag;
    if (blockIdx.x < 720) {
        int i = blockIdx.x * 256 + threadIdx.x;        // < 184320
        float v = f ? __bfloat162float(((const __hip_bfloat16*)Wsrc)[i])
                    : ((const float*)Wsrc)[i];
        Wb[i] = __float2bfloat16(v);
    } else if (threadIdx.x < CDIM) {
        int j = threadIdx.x;
        bfp[j] = f ? __bfloat162float(((const __hip_bfloat16*)bsrc)[j])
                   : ((const float*)bsrc)[j];
    }
}

// ---------------- fused transpose+GEMM ---------------------------------------------------------
// Out[o][p] = sum_s sum_c W[o][s*192+c] * x[c][p + dp(s)], staged per 32-c block in LDS.
__device__ __forceinline__ void gload16(const void* g, void* l) {
    __builtin_amdgcn_global_load_lds(
        (const __attribute__((address_space(1))) uint32_t*)g,
        (__attribute__((address_space(3))) uint32_t*)l, 16, 0, 0);
}

__global__ __launch_bounds__(256, 2) void fused_kernel(const void* __restrict__ xsrc,
                                                       const __hip_bfloat16* __restrict__ Wm,
                                                       const float* __restrict__ biasf,
                                                       void* __restrict__ outv,
                                                       const int* __restrict__ flag) {
    __shared__ char lds[WOFF + 2 * WBUF];   // 56256 B -> 2 blocks/CU
    char* xsl  = lds;
    char* ldsW = lds + WOFF;
    const int f = *flag;
    const int tid  = threadIdx.x;
    const int lane = tid & 63, wave = tid >> 6;
    const int quad = lane >> 4, l15 = lane & 15;

    // XCD-aware bijective swizzle: consecutive wg -> h-adjacent, L2-local halo reuse
    const int nwg  = (int)gridDim.x;                 // 2048, % 8 == 0
    const int bid0 = (int)blockIdx.x;
    const int wg   = (bid0 & 7) * (nwg >> 3) + (bid0 >> 3);

    const int bb = wg >> 9;                          // plane 0..3
    const int r  = wg & 511;
    const int h  = r >> 1;
    const int w0 = (r & 1) << 7;
    const int p0 = h * WI + w0;
    const int obase = (wave >> 1) * 96;
    const int nbase = (wave & 1) * 64;

    // W staging pointers (same layout as previous kernels)
    const char* gw[3];
    int ldsoff[3];
    #pragma unroll
    for (int t = 0; t < 3; ++t) {
        int chunk = tid + t * 256;
        int kq = chunk / 192, o = chunk % 192;
        gw[t] = (const char*)Wm + ((size_t)o * KDIM + kq * 8) * 2;
        ldsoff[t] = chunk * 16;
    }
    int aoff[6];
    #pragma unroll
    for (int mt = 0; mt < 6; ++mt) {
        int o = obase + mt * 16 + l15;
        aoff[mt] = (quad * 192 + o) * 16;
    }

    // B-fragment geometry: pl = local out-col 0..127
    int pxa[4]; bool w255[4], wzero[4];
    #pragma unroll
    for (int nt = 0; nt < 4; ++nt) {
        int pl = nbase + nt * 16 + l15;
        pxa[nt]   = (pl + 1) * ROW_B;                // px_local = pl+1 (center)
        w255[nt]  = ((w0 + pl) == 255);
        wzero[nt] = ((w0 + pl) == 0);
    }

    // staging geometry: main threads cover px_local 1..128 x 16 c each
    const int scc  = tid >> 7;                       // c-half 0/1
    const int spx  = (tid & 127) + 1;                // px_local 1..128
    const int scol = w0 + (tid & 127);               // global col, always 0..255
    // edge threads (tid<64) cover px_local 0 (col w0-1) and 129 (col w0+128)
    const int ec = tid >> 1, ee = tid & 1;
    int ecol = ee ? (w0 + 128) : (w0 - 1);
    if (ecol < 0) ecol = 0;
    if (ecol > 255) ecol = 255;                      // clamped cols are killed at consume
    const int epx = ee ? 129 : 0;

    const size_t esz = f ? 2u : 4u;
    const char* xp = (const char*)xsrc + (size_t)bb * CDIM * HW * esz;

    int hr[3];
    #pragma unroll
    for (int rr = 0; rr < 3; ++rr) {
        int v = h - 1 + rr;
        hr[rr] = v < 0 ? 0 : (v > 255 ? 255 : v);    // clamped rows are killed at consume
    }

    floatx4 acc[6][4];
    #pragma unroll
    for (int mt = 0; mt < 6; ++mt)
        #pragma unroll
        for (int nt = 0; nt < 4; ++nt)
            acc[mt][nt] = (floatx4){0.f, 0.f, 0.f, 0.f};

#define STAGE(JJ)                                                                          \
    {                                                                                      \
        const int c0 = (JJ) * 32;                                                          \
        _Pragma("unroll")                                                                  \
        for (int rr = 0; rr < 3; ++rr) {                                                   \
            uint32_t tmp[16];                                                              \
            const size_t rowoff = (size_t)hr[rr] * WI;                                     \
            if (f) {                                                                       \
                const uint16_t* xg = (const uint16_t*)xp;                                  \
                _Pragma("unroll")                                                          \
                for (int cc = 0; cc < 16; ++cc)                                            \
                    tmp[cc] = xg[(size_t)(c0 + scc * 16 + cc) * HW + rowoff + scol];       \
            } else {                                                                       \
                const float* xg = (const float*)xp;                                        \
                _Pragma("unroll")                                                          \
                for (int cc = 0; cc < 16; ++cc)                                            \
                    tmp[cc] = f2b(xg[(size_t)(c0 + scc * 16 + cc) * HW + rowoff + scol]);  \
            }                                                                              \
            uint4 q0, q1;                                                                  \
            q0.x = tmp[0] | (tmp[1] << 16);  q0.y = tmp[2] | (tmp[3] << 16);               \
            q0.z = tmp[4] | (tmp[5] << 16);  q0.w = tmp[6] | (tmp[7] << 16);               \
            q1.x = tmp[8] | (tmp[9] << 16);  q1.y = tmp[10] | (tmp[11] << 16);             \
            q1.z = tmp[12] | (tmp[13] << 16); q1.w = tmp[14] | (tmp[15] << 16);            \
            char* base = xsl + rr * SLICE_B + spx * ROW_B + scc * 32;                      \
            *(uint4*)(base)      = q0;                                                     \
            *(uint4*)(base + 16) = q1;                                                     \
        }                                                                                  \
        if (tid < 64) {                                                                    \
            _Pragma("unroll")                                                              \
            for (int rr = 0; rr < 3; ++rr) {                                               \
                const size_t gi = (size_t)(c0 + ec) * HW + (size_t)hr[rr] * WI + ecol;     \
                uint16_t v = f ? ((const uint16_t*)xp)[gi]                                 \
                               : f2b(((const float*)xp)[gi]);                              \
                *(uint16_t*)(xsl + rr * SLICE_B + epx * ROW_B + ec * 2) = v;               \
            }                                                                              \
        }                                                                                  \
    }

    // prologue: W(j=0,s=0) gload (oldest), then stage j=0, then full sync
    #pragma unroll
    for (int t = 0; t < 3; ++t) gload16(gw[t], ldsW + ldsoff[t]);
    STAGE(0)
    __syncthreads();

    for (int j = 0; j < 6; ++j) {
        #pragma unroll
        for (int s = 0; s < 5; ++s) {
            const int cur = (s & 1) * WBUF;
            __builtin_amdgcn_s_barrier();           // prev step's LDS reads done everywhere
            __builtin_amdgcn_sched_barrier(0);
            if (s < 4) {
                const int nxt = WBUF - cur;
                #pragma unroll
                for (int t = 0; t < 3; ++t)
                    gload16(gw[t] + (size_t)((s + 1) * 6 + j) * 64, ldsW + nxt + ldsoff[t]);
            }
            __builtin_amdgcn_sched_barrier(0);
            if (s < 4) asm volatile("s_waitcnt vmcnt(3)" ::: "memory");  // W(j,s) landed
            else       asm volatile("s_waitcnt vmcnt(0)" ::: "memory");
            __builtin_amdgcn_sched_barrier(0);
            __builtin_amdgcn_s_barrier();           // W(j,s) visible to all waves
            __builtin_amdgcn_sched_barrier(0);

            short8 af[6];
            #pragma unroll
            for (int mt = 0; mt < 6; ++mt)
                af[mt] = *(const short8*)(ldsW + cur + aoff[mt]);

            // B-fragments from LDS x-slices: slice/col-shift per s
            const int so   = (s == 3) ? 2 * SLICE_B : (s == 4) ? 0 : SLICE_B;
            const int dw80 = (s == 1) ? ROW_B : (s == 2) ? -ROW_B : 0;
            const bool skip = (s == 3 && h == 255) || (s == 4 && h == 0);
            short8 bf[4];
            #pragma unroll
            for (int nt = 0; nt < 4; ++nt) {
                short8 v = *(const short8*)(xsl + so + pxa[nt] + dw80 + quad * 16);
                const bool kill = skip || (s == 1 && w255[nt]) || (s == 2 && wzero[nt]);
                bf[nt] = kill ? (short8){0, 0, 0, 0, 0, 0, 0, 0} : v;
            }

            __builtin_amdgcn_s_setprio(1);
            #pragma unroll
            for (int mt = 0; mt < 6; ++mt)
                #pragma unroll
                for (int nt = 0; nt < 4; ++nt)
                    acc[mt][nt] = __builtin_amdgcn_mfma_f32_16x16x32_bf16(
                        af[mt], bf[nt], acc[mt][nt], 0, 0, 0);
            __builtin_amdgcn_s_setprio(0);
        }
        if (j < 5) {
            __syncthreads();                        // all reads of xs[j] and Wbuf done
            #pragma unroll
            for (int t = 0; t < 3; ++t)             // W(j+1, s=0) -> buf0
                gload16(gw[t] + (size_t)(j + 1) * 64, ldsW + ldsoff[t]);
            STAGE(j + 1)
            __syncthreads();                        // xs[j+1] (and W) visible
        }
    }

    // epilogue: + bias; D layout: row(o) = quad*4+reg, col(px) = lane&15
    #pragma unroll
    for (int mt = 0; mt < 6; ++mt) {
        int o0 = obase + mt * 16 + quad * 4;
        float bv[4];
        #pragma unroll
        for (int rr = 0; rr < 4; ++rr) bv[rr] = biasf[o0 + rr];
        #pragma unroll
        for (int nt = 0; nt < 4; ++nt) {
            int px = nbase + nt * 16 + l15;
            size_t base = ((size_t)(bb * CDIM + o0) * HW) + p0 + px;
            if (f) {
                __hip_bfloat16* out = (__hip_bfloat16*)outv;
                #pragma unroll
                for (int rr = 0; rr < 4; ++rr)
                    out[base + (size_t)rr * HW] = __float2bfloat16(acc[mt][nt][rr] + bv[rr]);
            } else {
                float* out = (float*)outv;
                #pragma unroll
                for (int rr = 0; rr < 4; ++rr)
                    out[base + (size_t)rr * HW] = acc[mt][nt][rr] + bv[rr];
            }
        }
    }
#undef STAGE
}

// ---------------- fallback: naive direct conv, dtype-aware, no big workspace -------------------
__global__ __launch_bounds__(256) void fallback_kernel(const void* __restrict__ xv,
                                                       const void* __restrict__ Wv,
                                                       const void* __restrict__ bv,
                                                       void* __restrict__ outv,
                                                       const int* __restrict__ flag) {
    __shared__ float Wl[KDIM];
    const int f = *flag;
    const int tid = threadIdx.x;
    const int bid = blockIdx.x;
    const int h = bid & 255;
    const int bo = bid >> 8;
    const int o = bo % CDIM;
    const int b = bo / CDIM;
    if (f) {
        const __hip_bfloat16* W16 = (const __hip_bfloat16*)Wv;
        for (int i = tid; i < KDIM; i += 256) Wl[i] = __bfloat162float(W16[(size_t)o * KDIM + i]);
    } else {
        const float* W32 = (const float*)Wv;
        for (int i = tid; i < KDIM; i += 256) Wl[i] = W32[(size_t)o * KDIM + i];
    }
    __syncthreads();
    const size_t pb = (size_t)b * CDIM * HW + (size_t)h * WI + tid;
    float acc = f ? __bfloat162float(((const __hip_bfloat16*)bv)[o]) : ((const float*)bv)[o];
    if (f) {
        const __hip_bfloat16* x = (const __hip_bfloat16*)xv;
        for (int c = 0; c < CDIM; ++c) {
            const __hip_bfloat16* xp = x + pb + (size_t)c * HW;
            float ctr = __bfloat162float(xp[0]);
            float rgt = (tid < 255) ? __bfloat162float(xp[1])   : 0.f;
            float lft = (tid > 0)   ? __bfloat162float(xp[-1])  : 0.f;
            float dwn = (h < 255)   ? __bfloat162float(xp[WI])  : 0.f;
            float up  = (h > 0)     ? __bfloat162float(xp[-WI]) : 0.f;
            acc += ctr * Wl[c] + rgt * Wl[192 + c] + lft * Wl[384 + c]
                 + dwn * Wl[576 + c] + up * Wl[768 + c];
        }
    } else {
        const float* x = (const float*)xv;
        for (int c = 0; c < CDIM; ++c) {
            const float* xp = x + pb + (size_t)c * HW;
            float ctr = xp[0];
            float rgt = (tid < 255) ? xp[1]   : 0.f;
            float lft = (tid > 0)   ? xp[-1]  : 0.f;
            float dwn = (h < 255)   ? xp[WI]  : 0.f;
            float up  = (h > 0)     ? xp[-WI] : 0.f;
            acc += ctr * Wl[c] + rgt * Wl[192 + c] + lft * Wl[384 + c]
                 + dwn * Wl[576 + c] + up * Wl[768 + c];
        }
    }
    size_t oidx = (size_t)bo * HW + (size_t)h * WI + tid;
    if (f) ((__hip_bfloat16*)outv)[oidx] = __float2bfloat16(acc);
    else   ((float*)outv)[oidx] = acc;
}

extern "C" void kernel_launch(void* const* d_in, const int* in_sizes, int n_in,
                              void* d_out, int out_size, void* d_ws, size_t ws_size,
                              hipStream_t stream) {
    const uint32_t* xw = (const uint32_t*)d_in[0];
    char* ws = (char*)d_ws;

    if (ws_size >= NEED_WS) {
        __hip_bfloat16* Wb = (__hip_bfloat16*)ws;
        float* bfp = (float*)(ws + OFF_BIAS);
        int* flag  = (int*)(ws + OFF_FLAG);
        detect_kernel<<<1, 256, 0, stream>>>(xw, flag);
        prep_kernel<<<721, 256, 0, stream>>>(d_in[1], d_in[2], Wb, bfp, flag);
        fused_kernel<<<2048, 256, 0, stream>>>(d_in[0], Wb, bfp, d_out, flag);
    } else {
        int* flag = (int*)ws;
        detect_kernel<<<1, 256, 0, stream>>>(xw, flag);
        fallback_kernel<<<4 * CDIM * 256, 256, 0, stream>>>(d_in[0], d_in[1], d_in[2],
                                                            d_out, flag);
    }
}